// Round 16
// baseline (69.902 us; speedup 1.0000x reference)
//
#include <hip/hip_runtime.h>
#include <hip/hip_bf16.h>
#include <math.h>

// Problem: B=8, M=N=4096, C=3, f32. Avg-Hausdorff (Chamfer), out (8,).
// d2(a,b) = sa + (sb - 2 a.b); paren term = rank-16 bf16 MFMA with fp32
// hi/lo splitting. Swapped operands (D = Target x Query) keep the
// target-min lane-local (R12). Structure identical to R14.
//
// R15 = CALIBRATION PROBE: k1 repeats its full {stage, loop, store} body
// REPS=8 times (barrier-fenced -> no cross-rep CSE/DCE; idempotent stores
// -> identical output). Purpose: surface k1 in the rocprof top-5 with its
// true counters, and decompose the 18.2 us budget:
//   k1_true = (dur_total - 18.2) / 7;  k2+gaps = 18.2 - k1_true.
constexpr int NB   = 8;
constexpr int NPTS = 4096;
constexpr int NSEG = 4;            // n segments per (dir,batch)
constexpr int NN   = NPTS / NSEG;  // 1024 target points per block
constexpr int REPS = 8;            // calibration multiplier

typedef __attribute__((ext_vector_type(8)))  short  short8;
typedef __attribute__((ext_vector_type(16))) float  f32x16;

__device__ inline unsigned short f2bf(float v) {
    __hip_bfloat16 t = __float2bfloat16(v);
    return *reinterpret_cast<unsigned short*>(&t);
}
__device__ inline float bf2f(unsigned short u) {
    __hip_bfloat16 t = *reinterpret_cast<__hip_bfloat16*>(&u);
    return __bfloat162float(t);
}

__global__ __launch_bounds__(256, 4) void mfma_min_kernel(
    const float* __restrict__ s1, const float* __restrict__ s2,
    float* __restrict__ pmin)
{
    __shared__ short8 blds[2048];   // 32 KB, slot-ordered target fragments

    int bid  = blockIdx.x;
    int nseg = bid & 3;
    int qb   = (bid >> 2) & 15;
    int g    = bid >> 6;               // dir*8 + batch
    int b    = g & 7, dir = g >> 3;

    const float* Q    = dir ? s2 : s1;   // query set
    const float* Tset = dir ? s1 : s2;   // target set

    int tid = threadIdx.x;
    int wid = tid >> 6, l = tid & 63;
    int c = l & 31, h = l >> 5;

    // ---- Encode this wave's 2 query fragments (64 queries) ----
    short8 qfr[2];
    #pragma unroll
    for (int f = 0; f < 2; ++f) {
        int qidx = qb * 256 + wid * 64 + f * 32 + c;
        const float* qp = Q + ((size_t)b * NPTS + qidx) * 3;
        float x = qp[0], y = qp[1], z = qp[2];
        unsigned short ahx = f2bf(x), ahy = f2bf(y), ahz = f2bf(z);
        if (h == 0) {
            unsigned short alx = f2bf(x - bf2f(ahx));
            unsigned short aly = f2bf(y - bf2f(ahy));
            unsigned short alz = f2bf(z - bf2f(ahz));
            unsigned short one = 0x3F80;
            qfr[f] = short8{(short)ahx,(short)ahy,(short)ahz,
                            (short)alx,(short)aly,(short)alz,(short)one,(short)one};
        } else {
            qfr[f] = short8{(short)ahx,(short)ahy,(short)ahz,0,0,0,0,0};
        }
    }

    const float* tsrc = Tset + ((size_t)b * NPTS + (size_t)nseg * NN) * 3;
    float* pg = pmin + ((size_t)g * NSEG + nseg) * NPTS;

    for (int rep = 0; rep < REPS; ++rep) {
        __syncthreads();               // fence: no cross-rep reordering/CSE

        // ---- Encode target segment into LDS (each thread: 4 points) ----
        #pragma unroll
        for (int k = 0; k < 4; ++k) {
            int p = k * 256 + tid;           // 0..1023
            float x = tsrc[p*3+0], y = tsrc[p*3+1], z = tsrc[p*3+2];
            float sq = fmaf(z, z, fmaf(y, y, x * x));
            float tx = -2.0f*x, ty = -2.0f*y, tz = -2.0f*z;
            unsigned short thx = f2bf(tx), thy = f2bf(ty), thz = f2bf(tz);
            unsigned short tlx = f2bf(tx - bf2f(thx));
            unsigned short tly = f2bf(ty - bf2f(thy));
            unsigned short tlz = f2bf(tz - bf2f(thz));
            unsigned short sqh = f2bf(sq);
            unsigned short sql = f2bf(sq - bf2f(sqh));
            short8 tLo = {(short)thx,(short)thy,(short)thz,(short)thx,(short)thy,(short)thz,(short)sqh,(short)sql};
            short8 tHi = {(short)tlx,(short)tly,(short)tlz,0,0,0,0,0};
            int slot = (p >> 5) * 64 + (p & 31);
            blds[slot]      = tLo;
            blds[slot + 32] = tHi;
        }
        __syncthreads();

        f32x16 zero, acc0, acc1;
        #pragma unroll
        for (int r = 0; r < 16; ++r) { zero[r] = 0.0f; acc0[r] = 3.4e38f; acc1[r] = 3.4e38f; }

        for (int i = 0; i < 16; ++i) {            // 32 target tiles, in pairs
            short8 t0 = blds[(2*i  ) * 64 + l];    // lane-contiguous b128
            short8 t1 = blds[(2*i+1) * 64 + l];
            {
                f32x16 d0 = __builtin_amdgcn_mfma_f32_32x32x16_bf16(t0, qfr[0], zero, 0, 0, 0);
                f32x16 d1 = __builtin_amdgcn_mfma_f32_32x32x16_bf16(t1, qfr[0], zero, 0, 0, 0);
                #pragma unroll
                for (int r = 0; r < 16; ++r)
                    acc0[r] = fminf(fminf(acc0[r], d0[r]), d1[r]);   // v_min3
            }
            {
                f32x16 d0 = __builtin_amdgcn_mfma_f32_32x32x16_bf16(t0, qfr[1], zero, 0, 0, 0);
                f32x16 d1 = __builtin_amdgcn_mfma_f32_32x32x16_bf16(t1, qfr[1], zero, 0, 0, 0);
                #pragma unroll
                for (int r = 0; r < 16; ++r)
                    acc1[r] = fminf(fminf(acc1[r], d0[r]), d1[r]);
            }
        }

        // ---- Lane-local fold + 1 cross-half shuffle; store query-min ----
        #pragma unroll
        for (int f = 0; f < 2; ++f) {
            f32x16& a = f ? acc1 : acc0;
            float v = a[0];
            #pragma unroll
            for (int r = 1; r < 16; ++r) v = fminf(v, a[r]);
            v = fminf(v, __shfl_xor(v, 32, 64));   // combine h halves
            if (h == 0)
                pg[qb * 256 + wid * 64 + f * 32 + c] = v;   // idempotent
        }
    }
}

// k2: one block per batch (8 x 1024 thr). Unchanged from R14.
__global__ __launch_bounds__(1024) void reduce_kernel(
    const float* __restrict__ s1, const float* __restrict__ s2,
    const float* __restrict__ pmin, float* __restrict__ out)
{
    int b = blockIdx.x;
    int t = threadIdx.x;               // float4 row-group, 0..1023

    float sum = 0.0f;
    #pragma unroll
    for (int dir = 0; dir < 2; ++dir) {
        int g = dir * NB + b;
        const float4* pg = reinterpret_cast<const float4*>(pmin + (size_t)g * NSEG * NPTS);
        float4 m = pg[t];
        #pragma unroll
        for (int s = 1; s < NSEG; ++s) {
            float4 v = pg[(size_t)s * 1024 + t];
            m.x = fminf(m.x, v.x); m.y = fminf(m.y, v.y);
            m.z = fminf(m.z, v.z); m.w = fminf(m.w, v.w);
        }
        const float* q = (dir ? s2 : s1) + ((size_t)b * NPTS + (size_t)4 * t) * 3;
        const float4* q4 = reinterpret_cast<const float4*>(q);
        float4 f0 = q4[0], f1 = q4[1], f2 = q4[2];
        float sa0 = fmaf(f0.z, f0.z, fmaf(f0.y, f0.y, f0.x * f0.x));
        float sa1 = fmaf(f1.y, f1.y, fmaf(f1.x, f1.x, f0.w * f0.w));
        float sa2 = fmaf(f2.x, f2.x, fmaf(f1.w, f1.w, f1.z * f1.z));
        float sa3 = fmaf(f2.w, f2.w, fmaf(f2.z, f2.z, f2.y * f2.y));
        sum += sqrtf(fmaxf(sa0 + m.x, 0.0f)) + sqrtf(fmaxf(sa1 + m.y, 0.0f))
             + sqrtf(fmaxf(sa2 + m.z, 0.0f)) + sqrtf(fmaxf(sa3 + m.w, 0.0f));
    }

    for (int off = 32; off > 0; off >>= 1)
        sum += __shfl_down(sum, off, 64);

    __shared__ float red[16];
    if ((t & 63) == 0) red[t >> 6] = sum;
    __syncthreads();
    if (t == 0) {
        float tt = 0.0f;
        #pragma unroll
        for (int w = 0; w < 16; ++w) tt += red[w];
        out[b] = tt * (1.0f / (float)NPTS);
    }
}

extern "C" void kernel_launch(void* const* d_in, const int* in_sizes, int n_in,
                              void* d_out, int out_size, void* d_ws, size_t ws_size,
                              hipStream_t stream) {
    const float* set1 = (const float*)d_in[0];
    const float* set2 = (const float*)d_in[1];
    float* out  = (float*)d_out;
    float* pmin = (float*)d_ws;    // 2*NB*NSEG*NPTS*4 = 1 MiB

    mfma_min_kernel<<<16 * 16 * NSEG, 256, 0, stream>>>(set1, set2, pmin);
    reduce_kernel<<<NB, 1024, 0, stream>>>(set1, set2, pmin, out);
}

// Round 17
// 18.204 us; speedup vs baseline: 3.8399x; 3.8399x over previous
//
#include <hip/hip_runtime.h>
#include <hip/hip_bf16.h>
#include <math.h>

// Problem: B=8, M=N=4096, C=3, f32. Avg-Hausdorff (Chamfer), out (8,).
// d2(a,b) = sa + (sb - 2 a.b); paren term = rank-16 bf16 MFMA with fp32
// hi/lo splitting (absmax 0.0, R9-R15). Swapped operands (D = T x Q) keep
// the target-min lane-local (R12). k1_true = 7.4 us (R15 calibration).
//
// R16: reduce-path diet. sa folded into k1's store (k2 loses raw-input
// loads); k2 widened to 64 blocks (was 8); tiny k3 combines partials.
constexpr int NB   = 8;
constexpr int NPTS = 4096;
constexpr int NSEG = 4;            // n segments per (dir,batch)
constexpr int NN   = NPTS / NSEG;  // 1024 target points per block

typedef __attribute__((ext_vector_type(8)))  short  short8;
typedef __attribute__((ext_vector_type(16))) float  f32x16;

__device__ inline unsigned short f2bf(float v) {
    __hip_bfloat16 t = __float2bfloat16(v);
    return *reinterpret_cast<unsigned short*>(&t);
}
__device__ inline float bf2f(unsigned short u) {
    __hip_bfloat16 t = *reinterpret_cast<__hip_bfloat16*>(&u);
    return __bfloat162float(t);
}

// k1: grid = 16 g x 16 qblk x 4 nseg = 1024 blocks (4/CU, 4 waves/SIMD).
// Unchanged from R14 except the tail stores sa + min (sa from the lane's
// own query coords, kept in registers from the qfr encode).
__global__ __launch_bounds__(256, 4) void mfma_min_kernel(
    const float* __restrict__ s1, const float* __restrict__ s2,
    float* __restrict__ pmin)
{
    __shared__ short8 blds[2048];   // 32 KB, slot-ordered target fragments

    int bid  = blockIdx.x;
    int nseg = bid & 3;
    int qb   = (bid >> 2) & 15;
    int g    = bid >> 6;               // dir*8 + batch
    int b    = g & 7, dir = g >> 3;

    const float* Q    = dir ? s2 : s1;   // query set
    const float* Tset = dir ? s1 : s2;   // target set

    int tid = threadIdx.x;
    int wid = tid >> 6, l = tid & 63;
    int c = l & 31, h = l >> 5;

    // ---- Encode target segment into LDS (each thread: 4 points) ----
    const float* tsrc = Tset + ((size_t)b * NPTS + (size_t)nseg * NN) * 3;
    #pragma unroll
    for (int k = 0; k < 4; ++k) {
        int p = k * 256 + tid;           // 0..1023
        float x = tsrc[p*3+0], y = tsrc[p*3+1], z = tsrc[p*3+2];
        float sq = fmaf(z, z, fmaf(y, y, x * x));
        float tx = -2.0f*x, ty = -2.0f*y, tz = -2.0f*z;
        unsigned short thx = f2bf(tx), thy = f2bf(ty), thz = f2bf(tz);
        unsigned short tlx = f2bf(tx - bf2f(thx));
        unsigned short tly = f2bf(ty - bf2f(thy));
        unsigned short tlz = f2bf(tz - bf2f(thz));
        unsigned short sqh = f2bf(sq);
        unsigned short sql = f2bf(sq - bf2f(sqh));
        short8 tLo = {(short)thx,(short)thy,(short)thz,(short)thx,(short)thy,(short)thz,(short)sqh,(short)sql};
        short8 tHi = {(short)tlx,(short)tly,(short)tlz,0,0,0,0,0};
        int slot = (p >> 5) * 64 + (p & 31);
        blds[slot]      = tLo;
        blds[slot + 32] = tHi;
    }

    // ---- Encode this wave's 2 query fragments; keep coords for sa ----
    short8 qfr[2]; float qx[2], qy[2], qz[2];
    #pragma unroll
    for (int f = 0; f < 2; ++f) {
        int qidx = qb * 256 + wid * 64 + f * 32 + c;
        const float* qp = Q + ((size_t)b * NPTS + qidx) * 3;
        float x = qp[0], y = qp[1], z = qp[2];
        qx[f] = x; qy[f] = y; qz[f] = z;
        unsigned short ahx = f2bf(x), ahy = f2bf(y), ahz = f2bf(z);
        if (h == 0) {
            unsigned short alx = f2bf(x - bf2f(ahx));
            unsigned short aly = f2bf(y - bf2f(ahy));
            unsigned short alz = f2bf(z - bf2f(ahz));
            unsigned short one = 0x3F80;
            qfr[f] = short8{(short)ahx,(short)ahy,(short)ahz,
                            (short)alx,(short)aly,(short)alz,(short)one,(short)one};
        } else {
            qfr[f] = short8{(short)ahx,(short)ahy,(short)ahz,0,0,0,0,0};
        }
    }
    __syncthreads();

    f32x16 zero, acc0, acc1;
    #pragma unroll
    for (int r = 0; r < 16; ++r) { zero[r] = 0.0f; acc0[r] = 3.4e38f; acc1[r] = 3.4e38f; }

    for (int i = 0; i < 16; ++i) {            // 32 target tiles, in pairs
        short8 t0 = blds[(2*i  ) * 64 + l];    // lane-contiguous b128
        short8 t1 = blds[(2*i+1) * 64 + l];
        {
            f32x16 d0 = __builtin_amdgcn_mfma_f32_32x32x16_bf16(t0, qfr[0], zero, 0, 0, 0);
            f32x16 d1 = __builtin_amdgcn_mfma_f32_32x32x16_bf16(t1, qfr[0], zero, 0, 0, 0);
            #pragma unroll
            for (int r = 0; r < 16; ++r)
                acc0[r] = fminf(fminf(acc0[r], d0[r]), d1[r]);   // v_min3
        }
        {
            f32x16 d0 = __builtin_amdgcn_mfma_f32_32x32x16_bf16(t0, qfr[1], zero, 0, 0, 0);
            f32x16 d1 = __builtin_amdgcn_mfma_f32_32x32x16_bf16(t1, qfr[1], zero, 0, 0, 0);
            #pragma unroll
            for (int r = 0; r < 16; ++r)
                acc1[r] = fminf(fminf(acc1[r], d0[r]), d1[r]);
        }
    }

    // ---- Lane-local fold + 1 cross-half shuffle; store sa + query-min ----
    float* pg = pmin + ((size_t)g * NSEG + nseg) * NPTS;
    #pragma unroll
    for (int f = 0; f < 2; ++f) {
        f32x16& a = f ? acc1 : acc0;
        float v = a[0];
        #pragma unroll
        for (int r = 1; r < 16; ++r) v = fminf(v, a[r]);
        v = fminf(v, __shfl_xor(v, 32, 64));   // combine h halves
        if (h == 0) {
            float sa = fmaf(qz[f], qz[f], fmaf(qy[f], qy[f], qx[f] * qx[f]));
            pg[qb * 256 + wid * 64 + f * 32 + c] = sa + v;   // 128B coalesced
        }
    }
}

// k2: grid = 16 g x 4 qchunk = 64 blocks x 256 thr. Per thread: float4 of
// 4 queries x 4 segs (consecutive b128 loads), min, clamp, sqrt, wave+block
// sum -> partial[g*4 + qchunk].
__global__ __launch_bounds__(256) void reduce_kernel(
    const float* __restrict__ pmin, float* __restrict__ partial)
{
    int bid = blockIdx.x;
    int qc  = bid & 3;
    int g   = bid >> 2;
    int t   = threadIdx.x;
    int col = qc * 256 + t;            // float4 column, 0..1023

    const float4* pg = reinterpret_cast<const float4*>(
        pmin + (size_t)g * NSEG * NPTS) + col;

    float4 m = pg[0];
    #pragma unroll
    for (int s = 1; s < NSEG; ++s) {
        float4 v = pg[(size_t)s * 1024];
        m.x = fminf(m.x, v.x); m.y = fminf(m.y, v.y);
        m.z = fminf(m.z, v.z); m.w = fminf(m.w, v.w);
    }
    float sum = sqrtf(fmaxf(m.x, 0.0f)) + sqrtf(fmaxf(m.y, 0.0f))
              + sqrtf(fmaxf(m.z, 0.0f)) + sqrtf(fmaxf(m.w, 0.0f));

    for (int off = 32; off > 0; off >>= 1)
        sum += __shfl_down(sum, off, 64);

    __shared__ float red[4];
    if ((t & 63) == 0) red[t >> 6] = sum;
    __syncthreads();
    if (t == 0) partial[bid] = red[0] + red[1] + red[2] + red[3];
}

// k3: 1 block, 64 threads: lane g<16 sums its 4 partials; lanes b<8 combine
// dir sums via shfl; out[b] = total / M.
__global__ __launch_bounds__(64) void final_kernel(
    const float* __restrict__ partial, float* __restrict__ out)
{
    int l = threadIdx.x;
    float s = 0.0f;
    if (l < 16) {
        #pragma unroll
        for (int j = 0; j < 4; ++j)
            s += partial[l * 4 + j];
    }
    float other = __shfl(s, l + 8, 64);    // lane b<8 gets g=8+b sum
    if (l < NB)
        out[l] = (s + other) * (1.0f / (float)NPTS);
}

extern "C" void kernel_launch(void* const* d_in, const int* in_sizes, int n_in,
                              void* d_out, int out_size, void* d_ws, size_t ws_size,
                              hipStream_t stream) {
    const float* set1 = (const float*)d_in[0];
    const float* set2 = (const float*)d_in[1];
    float* out     = (float*)d_out;
    float* pmin    = (float*)d_ws;                       // 1 MiB
    float* partial = pmin + (size_t)2 * NB * NSEG * NPTS;  // 64 floats

    mfma_min_kernel<<<16 * 16 * NSEG, 256, 0, stream>>>(set1, set2, pmin);
    reduce_kernel<<<16 * 4, 256, 0, stream>>>(pmin, partial);
    final_kernel<<<1, 64, 0, stream>>>(partial, out);
}

// Round 18
// 17.688 us; speedup vs baseline: 3.9519x; 1.0292x over previous
//
#include <hip/hip_runtime.h>
#include <hip/hip_bf16.h>
#include <math.h>

// Problem: B=8, M=N=4096, C=3, f32. Avg-Hausdorff (Chamfer), out (8,).
// d2(a,b) = sa + (sb - 2 a.b); paren term = rank-16 bf16 MFMA with fp32
// hi/lo splitting (absmax 0.0, R9-R16). Swapped operands (D = T x Q) keep
// the target-min lane-local (R12). k1 ~= 7.4-8.8 us (R15 calibration);
// launch overhead ~= 9 us of the 18.2 total (R15/R16 decomposition).
//
// R17: TWO dispatches. k1 unchanged (sa folded into its store, R16).
// k2+k3 merged: 8 blocks x 1024 thr read pmin only, write out[] directly.
constexpr int NB   = 8;
constexpr int NPTS = 4096;
constexpr int NSEG = 4;            // n segments per (dir,batch)
constexpr int NN   = NPTS / NSEG;  // 1024 target points per block

typedef __attribute__((ext_vector_type(8)))  short  short8;
typedef __attribute__((ext_vector_type(16))) float  f32x16;

__device__ inline unsigned short f2bf(float v) {
    __hip_bfloat16 t = __float2bfloat16(v);
    return *reinterpret_cast<unsigned short*>(&t);
}
__device__ inline float bf2f(unsigned short u) {
    __hip_bfloat16 t = *reinterpret_cast<__hip_bfloat16*>(&u);
    return __bfloat162float(t);
}

// k1: grid = 16 g x 16 qblk x 4 nseg = 1024 blocks (4/CU, 4 waves/SIMD).
// Per iter: 2 lane-contiguous ds_read_b128 + 4 MFMA(T,Q) + 32 min3.
// Tail: lane-local fold + 1 shfl; store sa + min (128B coalesced).
__global__ __launch_bounds__(256, 4) void mfma_min_kernel(
    const float* __restrict__ s1, const float* __restrict__ s2,
    float* __restrict__ pmin)
{
    __shared__ short8 blds[2048];   // 32 KB, slot-ordered target fragments

    int bid  = blockIdx.x;
    int nseg = bid & 3;
    int qb   = (bid >> 2) & 15;
    int g    = bid >> 6;               // dir*8 + batch
    int b    = g & 7, dir = g >> 3;

    const float* Q    = dir ? s2 : s1;   // query set
    const float* Tset = dir ? s1 : s2;   // target set

    int tid = threadIdx.x;
    int wid = tid >> 6, l = tid & 63;
    int c = l & 31, h = l >> 5;

    // ---- Encode target segment into LDS (each thread: 4 points) ----
    const float* tsrc = Tset + ((size_t)b * NPTS + (size_t)nseg * NN) * 3;
    #pragma unroll
    for (int k = 0; k < 4; ++k) {
        int p = k * 256 + tid;           // 0..1023
        float x = tsrc[p*3+0], y = tsrc[p*3+1], z = tsrc[p*3+2];
        float sq = fmaf(z, z, fmaf(y, y, x * x));
        float tx = -2.0f*x, ty = -2.0f*y, tz = -2.0f*z;
        unsigned short thx = f2bf(tx), thy = f2bf(ty), thz = f2bf(tz);
        unsigned short tlx = f2bf(tx - bf2f(thx));
        unsigned short tly = f2bf(ty - bf2f(thy));
        unsigned short tlz = f2bf(tz - bf2f(thz));
        unsigned short sqh = f2bf(sq);
        unsigned short sql = f2bf(sq - bf2f(sqh));
        short8 tLo = {(short)thx,(short)thy,(short)thz,(short)thx,(short)thy,(short)thz,(short)sqh,(short)sql};
        short8 tHi = {(short)tlx,(short)tly,(short)tlz,0,0,0,0,0};
        int slot = (p >> 5) * 64 + (p & 31);
        blds[slot]      = tLo;
        blds[slot + 32] = tHi;
    }

    // ---- Encode this wave's 2 query fragments; keep coords for sa ----
    short8 qfr[2]; float qx[2], qy[2], qz[2];
    #pragma unroll
    for (int f = 0; f < 2; ++f) {
        int qidx = qb * 256 + wid * 64 + f * 32 + c;
        const float* qp = Q + ((size_t)b * NPTS + qidx) * 3;
        float x = qp[0], y = qp[1], z = qp[2];
        qx[f] = x; qy[f] = y; qz[f] = z;
        unsigned short ahx = f2bf(x), ahy = f2bf(y), ahz = f2bf(z);
        if (h == 0) {
            unsigned short alx = f2bf(x - bf2f(ahx));
            unsigned short aly = f2bf(y - bf2f(ahy));
            unsigned short alz = f2bf(z - bf2f(ahz));
            unsigned short one = 0x3F80;
            qfr[f] = short8{(short)ahx,(short)ahy,(short)ahz,
                            (short)alx,(short)aly,(short)alz,(short)one,(short)one};
        } else {
            qfr[f] = short8{(short)ahx,(short)ahy,(short)ahz,0,0,0,0,0};
        }
    }
    __syncthreads();

    f32x16 zero, acc0, acc1;
    #pragma unroll
    for (int r = 0; r < 16; ++r) { zero[r] = 0.0f; acc0[r] = 3.4e38f; acc1[r] = 3.4e38f; }

    for (int i = 0; i < 16; ++i) {            // 32 target tiles, in pairs
        short8 t0 = blds[(2*i  ) * 64 + l];    // lane-contiguous b128
        short8 t1 = blds[(2*i+1) * 64 + l];
        {
            f32x16 d0 = __builtin_amdgcn_mfma_f32_32x32x16_bf16(t0, qfr[0], zero, 0, 0, 0);
            f32x16 d1 = __builtin_amdgcn_mfma_f32_32x32x16_bf16(t1, qfr[0], zero, 0, 0, 0);
            #pragma unroll
            for (int r = 0; r < 16; ++r)
                acc0[r] = fminf(fminf(acc0[r], d0[r]), d1[r]);   // v_min3
        }
        {
            f32x16 d0 = __builtin_amdgcn_mfma_f32_32x32x16_bf16(t0, qfr[1], zero, 0, 0, 0);
            f32x16 d1 = __builtin_amdgcn_mfma_f32_32x32x16_bf16(t1, qfr[1], zero, 0, 0, 0);
            #pragma unroll
            for (int r = 0; r < 16; ++r)
                acc1[r] = fminf(fminf(acc1[r], d0[r]), d1[r]);
        }
    }

    // ---- Lane-local fold + 1 cross-half shuffle; store sa + query-min ----
    float* pg = pmin + ((size_t)g * NSEG + nseg) * NPTS;
    #pragma unroll
    for (int f = 0; f < 2; ++f) {
        f32x16& a = f ? acc1 : acc0;
        float v = a[0];
        #pragma unroll
        for (int r = 1; r < 16; ++r) v = fminf(v, a[r]);
        v = fminf(v, __shfl_xor(v, 32, 64));   // combine h halves
        if (h == 0) {
            float sa = fmaf(qz[f], qz[f], fmaf(qy[f], qy[f], qx[f] * qx[f]));
            pg[qb * 256 + wid * 64 + f * 32 + c] = sa + v;   // 128B coalesced
        }
    }
}

// k2 (fused reduce+final): one block per batch, 1024 thr. Per thread: one
// float4 column x {2 dirs x 4 segs} coalesced loads, min, clamp, sqrt,
// block-sum -> out[b]. pmin already holds sa + min (R16 fold).
__global__ __launch_bounds__(1024) void reduce_kernel(
    const float* __restrict__ pmin, float* __restrict__ out)
{
    int b = blockIdx.x;
    int t = threadIdx.x;               // float4 column, 0..1023

    float sum = 0.0f;
    #pragma unroll
    for (int dir = 0; dir < 2; ++dir) {
        const float4* pg = reinterpret_cast<const float4*>(
            pmin + (size_t)(dir * NB + b) * NSEG * NPTS) + t;
        float4 m = pg[0];
        #pragma unroll
        for (int s = 1; s < NSEG; ++s) {
            float4 v = pg[(size_t)s * 1024];
            m.x = fminf(m.x, v.x); m.y = fminf(m.y, v.y);
            m.z = fminf(m.z, v.z); m.w = fminf(m.w, v.w);
        }
        sum += sqrtf(fmaxf(m.x, 0.0f)) + sqrtf(fmaxf(m.y, 0.0f))
             + sqrtf(fmaxf(m.z, 0.0f)) + sqrtf(fmaxf(m.w, 0.0f));
    }

    for (int off = 32; off > 0; off >>= 1)
        sum += __shfl_down(sum, off, 64);

    __shared__ float red[16];
    if ((t & 63) == 0) red[t >> 6] = sum;
    __syncthreads();
    if (t == 0) {
        float tt = 0.0f;
        #pragma unroll
        for (int w = 0; w < 16; ++w) tt += red[w];
        out[b] = tt * (1.0f / (float)NPTS);
    }
}

extern "C" void kernel_launch(void* const* d_in, const int* in_sizes, int n_in,
                              void* d_out, int out_size, void* d_ws, size_t ws_size,
                              hipStream_t stream) {
    const float* set1 = (const float*)d_in[0];
    const float* set2 = (const float*)d_in[1];
    float* out  = (float*)d_out;
    float* pmin = (float*)d_ws;    // 2*NB*NSEG*NPTS*4 = 1 MiB

    mfma_min_kernel<<<16 * 16 * NSEG, 256, 0, stream>>>(set1, set2, pmin);
    reduce_kernel<<<NB, 1024, 0, stream>>>(pmin, out);
}